// Round 1
// baseline (411.437 us; speedup 1.0000x reference)
//
#include <hip/hip_runtime.h>
#include <stdint.h>

#define NSEQ 512
#define CH   128
#define NN   (NSEQ*NSEQ)   // 262144

typedef unsigned short u16;
typedef __attribute__((ext_vector_type(8))) short bf16x8;  // 8 bf16 = 4 VGPRs
typedef __attribute__((ext_vector_type(4))) float f32x4;

__device__ __forceinline__ u16 f2bf(float x){
  uint32_t u = __float_as_uint(x);
  u += 0x7fffu + ((u >> 16) & 1u);      // round-to-nearest-even
  return (u16)(u >> 16);
}
__device__ __forceinline__ float bf2f(u16 h){
  return __uint_as_float(((uint32_t)h) << 16);
}
__device__ __forceinline__ float sigm(float x){
  return 1.0f / (1.0f + __expf(-x));
}

// ------------- k0: cast 6 weight matrices fp32 -> bf16 -------------
// ws slot order: 0=W_left 1=W_lgate 2=W_right 3=W_rgate 4=W_ogate 5=W_out
__global__ void k0_cvt(const float* __restrict__ w0, const float* __restrict__ w1,
                       const float* __restrict__ w2, const float* __restrict__ w3,
                       const float* __restrict__ w4, const float* __restrict__ w5,
                       u16* __restrict__ out)
{
  int mat = blockIdx.x >> 4;       // 16 blocks per 16384-elem matrix
  int blk = blockIdx.x & 15;
  const float* src = (mat==0)?w0:(mat==1)?w1:(mat==2)?w2:(mat==3)?w3:(mat==4)?w4:w5;
  int idx = (blk*256 + (int)threadIdx.x) * 4;
  float4 v = *(const float4*)(src + idx);
  uint2 pk;
  pk.x = (uint32_t)f2bf(v.x) | ((uint32_t)f2bf(v.y) << 16);
  pk.y = (uint32_t)f2bf(v.z) | ((uint32_t)f2bf(v.w) << 16);
  *(uint2*)(out + mat*16384 + idx) = pk;
}

// ------------- k1: LN(z) + 5 gated projections ---------------------
// 64 rows/block. Outputs: left_t/right_t in [c][row] bf16 (channel-major),
// og in [row][c] bf16.
__global__ __launch_bounds__(256) void k1_proj(
    const float* __restrict__ z, const float* __restrict__ pmask,
    const float* __restrict__ lnw, const float* __restrict__ lnb,
    const float* __restrict__ b_lg, const float* __restrict__ b_rg,
    const float* __restrict__ b_og, const u16* __restrict__ wts,
    u16* __restrict__ left_t, u16* __restrict__ right_t, u16* __restrict__ og)
{
  __shared__ __align__(16) u16 zn[64][136];   // 136 = 128 + 8 pad (272B rows, 16B-aligned)
  __shared__ __align__(16) u16 stg[128*72];   // [o][r] stage (144B rows) / reused as [r][o] [64][136]
  __shared__ float lnw_s[128], lnb_s[128], mask_s[64];

  const int t = threadIdx.x;
  const int row0 = blockIdx.x * 64;

  if (t < 32)       ((float4*)lnw_s)[t]     = ((const float4*)lnw)[t];
  else if (t < 64)  ((float4*)lnb_s)[t-32]  = ((const float4*)lnb)[t-32];
  else if (t < 80)  ((float4*)mask_s)[t-64] = ((const float4*)(pmask + row0))[t-64];
  __syncthreads();

  { // --- LayerNorm: thread = (row r, quarter q) covers 32 channels ---
    int r = t >> 2, q = t & 3;
    const float* zp = z + (size_t)(row0 + r) * CH + q * 32;
    float4 v[8];
    #pragma unroll
    for (int e=0;e<8;e++) v[e] = ((const float4*)zp)[e];
    float s = 0.f, sq = 0.f;
    #pragma unroll
    for (int e=0;e<8;e++){
      s  += v[e].x + v[e].y + v[e].z + v[e].w;
      sq += v[e].x*v[e].x + v[e].y*v[e].y + v[e].z*v[e].z + v[e].w*v[e].w;
    }
    s += __shfl_xor(s,1); sq += __shfl_xor(sq,1);
    s += __shfl_xor(s,2); sq += __shfl_xor(sq,2);
    float mu = s * (1.f/128.f);
    float rstd = rsqrtf(sq * (1.f/128.f) - mu*mu + 1e-5f);
    uint32_t pk[16];
    #pragma unroll
    for (int e=0;e<8;e++){
      int c = q*32 + e*4;
      float a0 = (v[e].x - mu)*rstd*lnw_s[c+0] + lnb_s[c+0];
      float a1 = (v[e].y - mu)*rstd*lnw_s[c+1] + lnb_s[c+1];
      float a2 = (v[e].z - mu)*rstd*lnw_s[c+2] + lnb_s[c+2];
      float a3 = (v[e].w - mu)*rstd*lnw_s[c+3] + lnb_s[c+3];
      pk[e*2+0] = (uint32_t)f2bf(a0) | ((uint32_t)f2bf(a1)<<16);
      pk[e*2+1] = (uint32_t)f2bf(a2) | ((uint32_t)f2bf(a3)<<16);
    }
    uint4* dst = (uint4*)&zn[r][q*32];
    #pragma unroll
    for (int e=0;e<4;e++) dst[e] = make_uint4(pk[e*4], pk[e*4+1], pk[e*4+2], pk[e*4+3]);
  }
  __syncthreads();

  const int lane = t & 63;
  const int w = t >> 6;          // wave owns output-col quadrant w*32..w*32+31
  const int lr = lane & 15;
  const int lg = lane >> 4;

  // A-fragments (shared by all 5 GEMMs): a[mi][kk] = zn rows mi*16+lr, k-chunk kk
  bf16x8 a[4][4];
  #pragma unroll
  for (int mi=0;mi<4;mi++)
    #pragma unroll
    for (int kk=0;kk<4;kk++)
      a[mi][kk] = *(const bf16x8*)&zn[mi*16 + lr][kk*32 + lg*8];

  f32x4 acc1[4][2], acc2[4][2];
  const f32x4 zero4 = {0.f,0.f,0.f,0.f};

  // ================= pass A: left = raw * sigmoid(lgate) * mask ===========
  #pragma unroll
  for (int mi=0;mi<4;mi++){ acc1[mi][0]=zero4; acc1[mi][1]=zero4; acc2[mi][0]=zero4; acc2[mi][1]=zero4; }
  #pragma unroll
  for (int kk=0;kk<4;kk++){
    #pragma unroll
    for (int n=0;n<2;n++){
      int o = w*32 + n*16 + lr;
      bf16x8 bl = *(const bf16x8*)&wts[0*16384 + o*128 + kk*32 + lg*8];
      bf16x8 bg = *(const bf16x8*)&wts[1*16384 + o*128 + kk*32 + lg*8];
      #pragma unroll
      for (int mi=0;mi<4;mi++){
        acc1[mi][n] = __builtin_amdgcn_mfma_f32_16x16x32_bf16(a[mi][kk], bl, acc1[mi][n], 0,0,0);
        acc2[mi][n] = __builtin_amdgcn_mfma_f32_16x16x32_bf16(a[mi][kk], bg, acc2[mi][n], 0,0,0);
      }
    }
  }
  #pragma unroll
  for (int n=0;n<2;n++){
    int o = w*32 + n*16 + lr;
    float bgv = b_lg[o];
    #pragma unroll
    for (int mi=0;mi<4;mi++){
      int r0 = mi*16 + lg*4;
      u16 tmp[4];
      #pragma unroll
      for (int g2=0; g2<4; g2++){
        float val = acc1[mi][n][g2] * sigm(acc2[mi][n][g2] + bgv) * mask_s[r0+g2];
        tmp[g2] = f2bf(val);
      }
      *(ushort4*)&stg[o*72 + r0] = make_ushort4(tmp[0],tmp[1],tmp[2],tmp[3]);
    }
  }
  __syncthreads();
  { // write left_t[c][row] coalesced
    int o = t >> 1, h = t & 1;
    const uint4* src = (const uint4*)&stg[o*72 + h*32];
    uint4* dst = (uint4*)(left_t + (size_t)o*NN + row0 + h*32);
    #pragma unroll
    for (int e=0;e<4;e++) dst[e] = src[e];
  }
  __syncthreads();

  // ================= pass B: right = raw * sigmoid(rgate) * mask ==========
  #pragma unroll
  for (int mi=0;mi<4;mi++){ acc1[mi][0]=zero4; acc1[mi][1]=zero4; acc2[mi][0]=zero4; acc2[mi][1]=zero4; }
  #pragma unroll
  for (int kk=0;kk<4;kk++){
    #pragma unroll
    for (int n=0;n<2;n++){
      int o = w*32 + n*16 + lr;
      bf16x8 bl = *(const bf16x8*)&wts[2*16384 + o*128 + kk*32 + lg*8];
      bf16x8 bg = *(const bf16x8*)&wts[3*16384 + o*128 + kk*32 + lg*8];
      #pragma unroll
      for (int mi=0;mi<4;mi++){
        acc1[mi][n] = __builtin_amdgcn_mfma_f32_16x16x32_bf16(a[mi][kk], bl, acc1[mi][n], 0,0,0);
        acc2[mi][n] = __builtin_amdgcn_mfma_f32_16x16x32_bf16(a[mi][kk], bg, acc2[mi][n], 0,0,0);
      }
    }
  }
  #pragma unroll
  for (int n=0;n<2;n++){
    int o = w*32 + n*16 + lr;
    float bgv = b_rg[o];
    #pragma unroll
    for (int mi=0;mi<4;mi++){
      int r0 = mi*16 + lg*4;
      u16 tmp[4];
      #pragma unroll
      for (int g2=0; g2<4; g2++){
        float val = acc1[mi][n][g2] * sigm(acc2[mi][n][g2] + bgv) * mask_s[r0+g2];
        tmp[g2] = f2bf(val);
      }
      *(ushort4*)&stg[o*72 + r0] = make_ushort4(tmp[0],tmp[1],tmp[2],tmp[3]);
    }
  }
  __syncthreads();
  {
    int o = t >> 1, h = t & 1;
    const uint4* src = (const uint4*)&stg[o*72 + h*32];
    uint4* dst = (uint4*)(right_t + (size_t)o*NN + row0 + h*32);
    #pragma unroll
    for (int e=0;e<4;e++) dst[e] = src[e];
  }
  __syncthreads();

  // ================= pass C: og = sigmoid(raw + b_og), [row][c] ===========
  #pragma unroll
  for (int mi=0;mi<4;mi++){ acc1[mi][0]=zero4; acc1[mi][1]=zero4; }
  #pragma unroll
  for (int kk=0;kk<4;kk++){
    #pragma unroll
    for (int n=0;n<2;n++){
      int o = w*32 + n*16 + lr;
      bf16x8 bo = *(const bf16x8*)&wts[4*16384 + o*128 + kk*32 + lg*8];
      #pragma unroll
      for (int mi=0;mi<4;mi++)
        acc1[mi][n] = __builtin_amdgcn_mfma_f32_16x16x32_bf16(a[mi][kk], bo, acc1[mi][n], 0,0,0);
    }
  }
  #pragma unroll
  for (int n=0;n<2;n++){
    int o = w*32 + n*16 + lr;
    float bgv = b_og[o];
    #pragma unroll
    for (int mi=0;mi<4;mi++){
      int r0 = mi*16 + lg*4;
      #pragma unroll
      for (int g2=0;g2<4;g2++)
        stg[(r0+g2)*136 + o] = f2bf(sigm(acc1[mi][n][g2] + bgv));   // [r][o] view
    }
  }
  __syncthreads();
  {
    int r = t >> 2, q = t & 3;
    const uint4* src = (const uint4*)&stg[r*136 + q*32];
    uint4* dst = (uint4*)(og + (size_t)(row0 + r)*CH + q*32);
    #pragma unroll
    for (int e=0;e<4;e++) dst[e] = src[e];
  }
}

// ------------- k2: per-channel 64x64x512 GEMM U_c = L_c * R_c^T ----------
// LDS XOR-swizzled (slot ^= row&7) so ds_read_b128 fragments are conflict-free.
__global__ __launch_bounds__(256) void k2_einsum(
    const u16* __restrict__ left_t, const u16* __restrict__ right_t,
    float* __restrict__ upd)
{
  __shared__ __align__(16) u16 ldsL[2][64*64];
  __shared__ __align__(16) u16 ldsR[2][64*64];
  const int t = threadIdx.x;
  const int lane = t & 63, w = t >> 6;
  const int wi = w >> 1, wj = w & 1;          // wave quadrant (32x32)
  const int lr = lane & 15, lg = lane >> 4;
  const int i0 = blockIdx.x * 64, j0 = blockIdx.y * 64;
  const int c  = blockIdx.z;
  const u16* L = left_t  + (size_t)c * NN;
  const u16* R = right_t + (size_t)c * NN;

  const int srow = t >> 3;   // 0..31
  const int ssl  = t & 7;    // 16B slot in row

  f32x4 acc[2][2];
  const f32x4 zero4 = {0.f,0.f,0.f,0.f};
  acc[0][0]=zero4; acc[0][1]=zero4; acc[1][0]=zero4; acc[1][1]=zero4;

  { // stage k-tile 0
    #pragma unroll
    for (int q=0;q<2;q++){
      int row = q*32 + srow;
      int sw = ssl ^ (row & 7);
      uint4 vL = *(const uint4*)&L[(size_t)(i0+row)*NSEQ + ssl*8];
      uint4 vR = *(const uint4*)&R[(size_t)(j0+row)*NSEQ + ssl*8];
      *(uint4*)&ldsL[0][row*64 + sw*8] = vL;
      *(uint4*)&ldsR[0][row*64 + sw*8] = vR;
    }
  }
  __syncthreads();

  for (int kt=0; kt<8; kt++){
    const int buf = kt & 1;
    uint4 pL[2], pR[2];
    if (kt < 7){                      // issue next-tile loads early (latency hides under MFMA)
      int k0 = (kt+1)*64;
      #pragma unroll
      for (int q=0;q<2;q++){
        int row = q*32 + srow;
        pL[q] = *(const uint4*)&L[(size_t)(i0+row)*NSEQ + k0 + ssl*8];
        pR[q] = *(const uint4*)&R[(size_t)(j0+row)*NSEQ + k0 + ssl*8];
      }
    }
    #pragma unroll
    for (int kk=0;kk<2;kk++){
      bf16x8 af[2], bfr[2];
      #pragma unroll
      for (int mi=0;mi<2;mi++){
        int row = wi*32 + mi*16 + lr;
        af[mi] = *(const bf16x8*)&ldsL[buf][row*64 + (((kk*4+lg) ^ (row&7)))*8];
      }
      #pragma unroll
      for (int nj=0;nj<2;nj++){
        int row = wj*32 + nj*16 + lr;
        bfr[nj] = *(const bf16x8*)&ldsR[buf][row*64 + (((kk*4+lg) ^ (row&7)))*8];
      }
      #pragma unroll
      for (int mi=0;mi<2;mi++)
        #pragma unroll
        for (int nj=0;nj<2;nj++)
          acc[mi][nj] = __builtin_amdgcn_mfma_f32_16x16x32_bf16(af[mi], bfr[nj], acc[mi][nj], 0,0,0);
    }
    if (kt < 7){
      #pragma unroll
      for (int q=0;q<2;q++){
        int row = q*32 + srow;
        int sw = ssl ^ (row & 7);
        *(uint4*)&ldsL[buf^1][row*64 + sw*8] = pL[q];
        *(uint4*)&ldsR[buf^1][row*64 + sw*8] = pR[q];
      }
    }
    __syncthreads();
  }

  const float scale = 0.044194173824159216f;   // 1/sqrt(512)
  #pragma unroll
  for (int mi=0;mi<2;mi++){
    #pragma unroll
    for (int nj=0;nj<2;nj++){
      int gj = j0 + wj*32 + nj*16 + lr;
      #pragma unroll
      for (int g2=0;g2<4;g2++){
        int gi = i0 + wi*32 + mi*16 + lg*4 + g2;
        upd[(size_t)c*NN + (size_t)gi*NSEQ + gj] = acc[mi][nj][g2] * scale;
      }
    }
  }
}

// ------------- k3a: LN over c of update [c][i][j] -> znu [i][j][c] bf16 ---
__global__ __launch_bounds__(256) void k3a_ln(
    const float* __restrict__ upd, const float* __restrict__ onw,
    const float* __restrict__ onb, u16* __restrict__ znu)
{
  __shared__ float u[128*128];     // [c][j] 64KB
  __shared__ float onw_s[128], onb_s[128];
  const int t = threadIdx.x;
  const int i = blockIdx.x;
  const int j0 = blockIdx.y * 128;

  if (t < 32)      ((float4*)onw_s)[t]    = ((const float4*)onw)[t];
  else if (t < 64) ((float4*)onb_s)[t-32] = ((const float4*)onb)[t-32];

  {
    int cr = t >> 1, h = t & 1;
    const float4* src = (const float4*)(upd + (size_t)cr*NN + (size_t)i*NSEQ + j0 + h*64);
    float4* dst = (float4*)&u[cr*128 + h*64];
    #pragma unroll
    for (int e=0;e<16;e++) dst[e] = src[e];
  }
  __syncthreads();

  int j = t >> 1, h = t & 1;
  float s = 0.f, sq = 0.f;
  #pragma unroll
  for (int e=0;e<64;e++){
    float v = u[(h*64+e)*128 + j];
    s += v; sq += v*v;
  }
  s += __shfl_xor(s,1); sq += __shfl_xor(sq,1);
  float mu = s * (1.f/128.f);
  float rstd = rsqrtf(sq * (1.f/128.f) - mu*mu + 1e-5f);

  uint32_t pk[32];
  #pragma unroll
  for (int e=0;e<64;e+=2){
    int c0 = h*64 + e;
    float v0 = (u[c0*128 + j]     - mu)*rstd*onw_s[c0]   + onb_s[c0];
    float v1 = (u[(c0+1)*128 + j] - mu)*rstd*onw_s[c0+1] + onb_s[c0+1];
    pk[e>>1] = (uint32_t)f2bf(v0) | ((uint32_t)f2bf(v1)<<16);
  }
  uint4* dst = (uint4*)(znu + ((size_t)i*NSEQ + j0 + j)*CH + h*64);
  #pragma unroll
  for (int e=0;e<8;e++) dst[e] = make_uint4(pk[e*4], pk[e*4+1], pk[e*4+2], pk[e*4+3]);
}

// ------------- k3b: out = (znu @ W_out^T) * og * mask ---------------------
__global__ __launch_bounds__(256) void k3b_out(
    const u16* __restrict__ znu, const u16* __restrict__ og,
    const float* __restrict__ pmask, const u16* __restrict__ wts,
    float* __restrict__ out)
{
  __shared__ __align__(16) u16 zn[64][136];
  __shared__ __align__(16) float so[64][132];   // [r][o] fp32 stage
  __shared__ float mask_s[64];
  const int t = threadIdx.x;
  const int row0 = blockIdx.x * 64;

  if (t < 16) ((float4*)mask_s)[t] = ((const float4*)(pmask + row0))[t];
  {
    int r = t >> 2, q = t & 3;
    const uint4* src = (const uint4*)(znu + (size_t)(row0 + r)*CH + q*32);
    uint4* dst = (uint4*)&zn[r][q*32];
    #pragma unroll
    for (int e=0;e<4;e++) dst[e] = src[e];
  }
  __syncthreads();

  const int lane = t & 63, w = t >> 6;
  const int lr = lane & 15, lg = lane >> 4;

  bf16x8 a[4][4];
  #pragma unroll
  for (int mi=0;mi<4;mi++)
    #pragma unroll
    for (int kk=0;kk<4;kk++)
      a[mi][kk] = *(const bf16x8*)&zn[mi*16 + lr][kk*32 + lg*8];

  f32x4 acc[4][2];
  const f32x4 zero4 = {0.f,0.f,0.f,0.f};
  #pragma unroll
  for (int mi=0;mi<4;mi++){ acc[mi][0] = zero4; acc[mi][1] = zero4; }

  #pragma unroll
  for (int kk=0;kk<4;kk++){
    #pragma unroll
    for (int n=0;n<2;n++){
      int o = w*32 + n*16 + lr;
      bf16x8 b = *(const bf16x8*)&wts[5*16384 + o*128 + kk*32 + lg*8];
      #pragma unroll
      for (int mi=0;mi<4;mi++)
        acc[mi][n] = __builtin_amdgcn_mfma_f32_16x16x32_bf16(a[mi][kk], b, acc[mi][n], 0,0,0);
    }
  }
  #pragma unroll
  for (int n=0;n<2;n++){
    int o = w*32 + n*16 + lr;
    #pragma unroll
    for (int mi=0;mi<4;mi++){
      int r0 = mi*16 + lg*4;
      #pragma unroll
      for (int g2=0;g2<4;g2++)
        so[r0+g2][o] = acc[mi][n][g2];
    }
  }
  __syncthreads();
  {
    int r = t >> 2, q = t & 3;
    float m = mask_s[r];
    const u16* ogp = og + (size_t)(row0 + r)*CH + q*32;
    uint4 o4[4];
    #pragma unroll
    for (int e=0;e<4;e++) o4[e] = ((const uint4*)ogp)[e];
    const u16* oh = (const u16*)o4;
    float* dst = out + (size_t)(row0 + r)*CH + q*32;
    #pragma unroll
    for (int e=0;e<8;e++){
      float4 v;
      v.x = so[r][q*32 + e*4+0] * bf2f(oh[e*4+0]) * m;
      v.y = so[r][q*32 + e*4+1] * bf2f(oh[e*4+1]) * m;
      v.z = so[r][q*32 + e*4+2] * bf2f(oh[e*4+2]) * m;
      v.w = so[r][q*32 + e*4+3] * bf2f(oh[e*4+3]) * m;
      ((float4*)dst)[e] = v;
    }
  }
}

// --------------------------- launcher ------------------------------------
extern "C" void kernel_launch(void* const* d_in, const int* in_sizes, int n_in,
                              void* d_out, int out_size, void* d_ws, size_t ws_size,
                              hipStream_t stream)
{
  const float* z       = (const float*)d_in[0];
  const float* pmask   = (const float*)d_in[1];
  const float* lnw     = (const float*)d_in[2];
  const float* lnb     = (const float*)d_in[3];
  const float* W_left  = (const float*)d_in[4];
  const float* W_right = (const float*)d_in[5];
  const float* W_lgate = (const float*)d_in[6];
  const float* b_lgate = (const float*)d_in[7];
  const float* W_rgate = (const float*)d_in[8];
  const float* b_rgate = (const float*)d_in[9];
  const float* onw     = (const float*)d_in[10];
  const float* onb     = (const float*)d_in[11];
  const float* W_out   = (const float*)d_in[12];
  const float* W_ogate = (const float*)d_in[13];
  const float* b_ogate = (const float*)d_in[14];

  // workspace layout (bytes): left_t 64MB | right_t 64MB | og 64MB | weights
  uint8_t* ws = (uint8_t*)d_ws;
  u16* left_t  = (u16*)(ws);
  u16* right_t = (u16*)(ws + (size_t)67108864);
  u16* ogb     = (u16*)(ws + (size_t)134217728);
  u16* wts     = (u16*)(ws + (size_t)201326592);
  float* upd   = (float*)d_out;   // d_out doubles as update[c][i][j] scratch

  k0_cvt<<<96, 256, 0, stream>>>(W_left, W_lgate, W_right, W_rgate, W_ogate, W_out, wts);
  k1_proj<<<4096, 256, 0, stream>>>(z, pmask, lnw, lnb, b_lgate, b_rgate, b_ogate,
                                    wts, left_t, right_t, ogb);
  k2_einsum<<<dim3(8,8,128), 256, 0, stream>>>(left_t, right_t, upd);
  k3a_ln<<<dim3(512,4), 256, 0, stream>>>(upd, onw, onb, left_t /*znu reuses left_t*/);
  k3b_out<<<4096, 256, 0, stream>>>(left_t, ogb, pmask, wts, (float*)d_out);
}

// Round 3
// 373.939 us; speedup vs baseline: 1.1003x; 1.1003x over previous
//
#include <hip/hip_runtime.h>
#include <stdint.h>

#define NSEQ 512
#define CH   128
#define NN   (NSEQ*NSEQ)   // 262144

typedef unsigned short u16;
typedef __attribute__((ext_vector_type(8))) short bf16x8;  // 8 bf16 = 4 VGPRs
typedef __attribute__((ext_vector_type(4))) float f32x4;

__device__ __forceinline__ u16 f2bf(float x){          // RNE
  uint32_t u = __float_as_uint(x);
  u += 0x7fffu + ((u >> 16) & 1u);
  return (u16)(u >> 16);
}
__device__ __forceinline__ float bf2f(u16 h){
  return __uint_as_float(((uint32_t)h) << 16);
}
__device__ __forceinline__ uint32_t cvtpk(float lo, float hi){  // bf16(lo)|bf16(hi)<<16
  uint32_t r;
  asm volatile("v_cvt_pk_bf16_f32 %0, %1, %2" : "=v"(r) : "v"(lo), "v"(hi));
  return r;
}
__device__ __forceinline__ float sigm(float x){
  return __builtin_amdgcn_rcpf(1.0f + __expf(-x));
}

// ------------- k0: cast 6 weight matrices fp32 -> bf16 -------------
// slot order: 0=W_left 1=W_lgate 2=W_right 3=W_rgate 4=W_ogate 5=W_out
__global__ void k0_cvt(const float* __restrict__ w0, const float* __restrict__ w1,
                       const float* __restrict__ w2, const float* __restrict__ w3,
                       const float* __restrict__ w4, const float* __restrict__ w5,
                       u16* __restrict__ out)
{
  int mat = blockIdx.x >> 4;
  int blk = blockIdx.x & 15;
  const float* src = (mat==0)?w0:(mat==1)?w1:(mat==2)?w2:(mat==3)?w3:(mat==4)?w4:w5;
  int idx = (blk*256 + (int)threadIdx.x) * 4;
  float4 v = *(const float4*)(src + idx);
  uint2 pk;
  pk.x = cvtpk(v.x, v.y);
  pk.y = cvtpk(v.z, v.w);
  *(uint2*)(out + mat*16384 + idx) = pk;
}

// ------------- k1: LN(z) + 5 gated projections ---------------------
// 64 rows/block. left_t/right_t channel-major [c][row]; og row-major [row][c].
__global__ __launch_bounds__(256) void k1_proj(
    const float* __restrict__ z, const float* __restrict__ pmask,
    const float* __restrict__ lnw, const float* __restrict__ lnb,
    const float* __restrict__ b_lg, const float* __restrict__ b_rg,
    const float* __restrict__ b_og, const u16* __restrict__ wts,
    u16* __restrict__ left_t, u16* __restrict__ right_t, u16* __restrict__ og)
{
  __shared__ __align__(16) u16 zn[64][136];
  __shared__ __align__(16) u16 stg[128*72];   // [o][r] stage; pass C uses [r][o] 64x136
  __shared__ float lnw_s[128], lnb_s[128], mask_s[64];

  const int t = threadIdx.x;
  const int row0 = blockIdx.x * 64;

  if (t < 32)       ((float4*)lnw_s)[t]     = ((const float4*)lnw)[t];
  else if (t < 64)  ((float4*)lnb_s)[t-32]  = ((const float4*)lnb)[t-32];
  else if (t < 80)  ((float4*)mask_s)[t-64] = ((const float4*)(pmask + row0))[t-64];
  __syncthreads();

  { // --- LayerNorm: thread = (row r, quarter q) covers 32 channels ---
    int r = t >> 2, q = t & 3;
    const float* zp = z + (size_t)(row0 + r) * CH + q * 32;
    float4 v[8];
    #pragma unroll
    for (int e=0;e<8;e++) v[e] = ((const float4*)zp)[e];
    float s = 0.f, sq = 0.f;
    #pragma unroll
    for (int e=0;e<8;e++){
      s  += v[e].x + v[e].y + v[e].z + v[e].w;
      sq += v[e].x*v[e].x + v[e].y*v[e].y + v[e].z*v[e].z + v[e].w*v[e].w;
    }
    s += __shfl_xor(s,1); sq += __shfl_xor(sq,1);
    s += __shfl_xor(s,2); sq += __shfl_xor(sq,2);
    float mu = s * (1.f/128.f);
    float rstd = __builtin_amdgcn_rsqf(sq * (1.f/128.f) - mu*mu + 1e-5f);
    uint32_t pk[16];
    #pragma unroll
    for (int e=0;e<8;e++){
      int c = q*32 + e*4;
      float a0 = (v[e].x - mu)*rstd*lnw_s[c+0] + lnb_s[c+0];
      float a1 = (v[e].y - mu)*rstd*lnw_s[c+1] + lnb_s[c+1];
      float a2 = (v[e].z - mu)*rstd*lnw_s[c+2] + lnb_s[c+2];
      float a3 = (v[e].w - mu)*rstd*lnw_s[c+3] + lnb_s[c+3];
      pk[e*2+0] = cvtpk(a0, a1);
      pk[e*2+1] = cvtpk(a2, a3);
    }
    uint4* dst = (uint4*)&zn[r][q*32];
    #pragma unroll
    for (int e=0;e<4;e++) dst[e] = make_uint4(pk[e*4], pk[e*4+1], pk[e*4+2], pk[e*4+3]);
  }
  __syncthreads();

  const int lane = t & 63;
  const int w = t >> 6;
  const int lr = lane & 15;
  const int lg = lane >> 4;

  bf16x8 a[4][4];
  #pragma unroll
  for (int mi=0;mi<4;mi++)
    #pragma unroll
    for (int kk=0;kk<4;kk++)
      a[mi][kk] = *(const bf16x8*)&zn[mi*16 + lr][kk*32 + lg*8];

  f32x4 acc1[4][2], acc2[4][2];
  const f32x4 zero4 = {0.f,0.f,0.f,0.f};

  // ===== pass A: left = raw * sigmoid(lgate) * mask =====
  #pragma unroll
  for (int mi=0;mi<4;mi++){ acc1[mi][0]=zero4; acc1[mi][1]=zero4; acc2[mi][0]=zero4; acc2[mi][1]=zero4; }
  #pragma unroll
  for (int kk=0;kk<4;kk++){
    #pragma unroll
    for (int n=0;n<2;n++){
      int o = w*32 + n*16 + lr;
      bf16x8 bl = *(const bf16x8*)&wts[0*16384 + o*128 + kk*32 + lg*8];
      bf16x8 bg = *(const bf16x8*)&wts[1*16384 + o*128 + kk*32 + lg*8];
      #pragma unroll
      for (int mi=0;mi<4;mi++){
        acc1[mi][n] = __builtin_amdgcn_mfma_f32_16x16x32_bf16(a[mi][kk], bl, acc1[mi][n], 0,0,0);
        acc2[mi][n] = __builtin_amdgcn_mfma_f32_16x16x32_bf16(a[mi][kk], bg, acc2[mi][n], 0,0,0);
      }
    }
  }
  #pragma unroll
  for (int n=0;n<2;n++){
    int o = w*32 + n*16 + lr;
    float bgv = b_lg[o];
    #pragma unroll
    for (int mi=0;mi<4;mi++){
      int r0 = mi*16 + lg*4;
      float v0 = acc1[mi][n][0] * sigm(acc2[mi][n][0] + bgv) * mask_s[r0+0];
      float v1 = acc1[mi][n][1] * sigm(acc2[mi][n][1] + bgv) * mask_s[r0+1];
      float v2 = acc1[mi][n][2] * sigm(acc2[mi][n][2] + bgv) * mask_s[r0+2];
      float v3 = acc1[mi][n][3] * sigm(acc2[mi][n][3] + bgv) * mask_s[r0+3];
      *(uint2*)&stg[o*72 + r0] = make_uint2(cvtpk(v0,v1), cvtpk(v2,v3));
    }
  }
  __syncthreads();
  {
    int o = t >> 1, h = t & 1;
    const uint4* src = (const uint4*)&stg[o*72 + h*32];
    uint4* dst = (uint4*)(left_t + (size_t)o*NN + row0 + h*32);
    #pragma unroll
    for (int e=0;e<4;e++) dst[e] = src[e];
  }
  __syncthreads();

  // ===== pass B: right = raw * sigmoid(rgate) * mask =====
  #pragma unroll
  for (int mi=0;mi<4;mi++){ acc1[mi][0]=zero4; acc1[mi][1]=zero4; acc2[mi][0]=zero4; acc2[mi][1]=zero4; }
  #pragma unroll
  for (int kk=0;kk<4;kk++){
    #pragma unroll
    for (int n=0;n<2;n++){
      int o = w*32 + n*16 + lr;
      bf16x8 bl = *(const bf16x8*)&wts[2*16384 + o*128 + kk*32 + lg*8];
      bf16x8 bg = *(const bf16x8*)&wts[3*16384 + o*128 + kk*32 + lg*8];
      #pragma unroll
      for (int mi=0;mi<4;mi++){
        acc1[mi][n] = __builtin_amdgcn_mfma_f32_16x16x32_bf16(a[mi][kk], bl, acc1[mi][n], 0,0,0);
        acc2[mi][n] = __builtin_amdgcn_mfma_f32_16x16x32_bf16(a[mi][kk], bg, acc2[mi][n], 0,0,0);
      }
    }
  }
  #pragma unroll
  for (int n=0;n<2;n++){
    int o = w*32 + n*16 + lr;
    float bgv = b_rg[o];
    #pragma unroll
    for (int mi=0;mi<4;mi++){
      int r0 = mi*16 + lg*4;
      float v0 = acc1[mi][n][0] * sigm(acc2[mi][n][0] + bgv) * mask_s[r0+0];
      float v1 = acc1[mi][n][1] * sigm(acc2[mi][n][1] + bgv) * mask_s[r0+1];
      float v2 = acc1[mi][n][2] * sigm(acc2[mi][n][2] + bgv) * mask_s[r0+2];
      float v3 = acc1[mi][n][3] * sigm(acc2[mi][n][3] + bgv) * mask_s[r0+3];
      *(uint2*)&stg[o*72 + r0] = make_uint2(cvtpk(v0,v1), cvtpk(v2,v3));
    }
  }
  __syncthreads();
  {
    int o = t >> 1, h = t & 1;
    const uint4* src = (const uint4*)&stg[o*72 + h*32];
    uint4* dst = (uint4*)(right_t + (size_t)o*NN + row0 + h*32);
    #pragma unroll
    for (int e=0;e<4;e++) dst[e] = src[e];
  }
  __syncthreads();

  // ===== pass C: og = sigmoid(raw + b_og), row-major [row][c] (R1-proven) =====
  #pragma unroll
  for (int mi=0;mi<4;mi++){ acc1[mi][0]=zero4; acc1[mi][1]=zero4; }
  #pragma unroll
  for (int kk=0;kk<4;kk++){
    #pragma unroll
    for (int n=0;n<2;n++){
      int o = w*32 + n*16 + lr;
      bf16x8 bo = *(const bf16x8*)&wts[4*16384 + o*128 + kk*32 + lg*8];
      #pragma unroll
      for (int mi=0;mi<4;mi++)
        acc1[mi][n] = __builtin_amdgcn_mfma_f32_16x16x32_bf16(a[mi][kk], bo, acc1[mi][n], 0,0,0);
    }
  }
  #pragma unroll
  for (int n=0;n<2;n++){
    int o = w*32 + n*16 + lr;
    float bgv = b_og[o];
    #pragma unroll
    for (int mi=0;mi<4;mi++){
      int r0 = mi*16 + lg*4;
      #pragma unroll
      for (int g2=0;g2<4;g2++)
        stg[(r0+g2)*136 + o] = f2bf(sigm(acc1[mi][n][g2] + bgv));   // [r][o] view
    }
  }
  __syncthreads();
  {
    int r = t >> 2, q = t & 3;
    const uint4* src = (const uint4*)&stg[r*136 + q*32];
    uint4* dst = (uint4*)(og + (size_t)(row0 + r)*CH + q*32);
    #pragma unroll
    for (int e=0;e<4;e++) dst[e] = src[e];
  }
}

// ------------- k2: per-channel 64x64x512 GEMM, bf16 output ----------------
__global__ __launch_bounds__(256) void k2_einsum(
    const u16* __restrict__ left_t, const u16* __restrict__ right_t,
    u16* __restrict__ upd16)
{
  __shared__ __align__(16) u16 lds_raw[16384];   // 32KB: L dbuf | R dbuf; reused as stage
  const int t = threadIdx.x;
  const int lane = t & 63, w = t >> 6;
  const int wi = w >> 1, wj = w & 1;
  const int lr = lane & 15, lg = lane >> 4;
  const int i0 = blockIdx.x * 64, j0 = blockIdx.y * 64;
  const int c  = blockIdx.z;
  const u16* L = left_t  + (size_t)c * NN;
  const u16* R = right_t + (size_t)c * NN;

  const int srow = t >> 3;
  const int ssl  = t & 7;

  f32x4 acc[2][2];
  const f32x4 zero4 = {0.f,0.f,0.f,0.f};
  acc[0][0]=zero4; acc[0][1]=zero4; acc[1][0]=zero4; acc[1][1]=zero4;

  u16* ldsL = lds_raw;          // [2][4096]
  u16* ldsR = lds_raw + 8192;   // [2][4096]

  {
    #pragma unroll
    for (int q=0;q<2;q++){
      int row = q*32 + srow;
      int sw = ssl ^ (row & 7);
      uint4 vL = *(const uint4*)&L[(size_t)(i0+row)*NSEQ + ssl*8];
      uint4 vR = *(const uint4*)&R[(size_t)(j0+row)*NSEQ + ssl*8];
      *(uint4*)&ldsL[row*64 + sw*8] = vL;
      *(uint4*)&ldsR[row*64 + sw*8] = vR;
    }
  }
  __syncthreads();

  for (int kt=0; kt<8; kt++){
    const int buf = kt & 1;
    uint4 pL[2], pR[2];
    if (kt < 7){
      int k0 = (kt+1)*64;
      #pragma unroll
      for (int q=0;q<2;q++){
        int row = q*32 + srow;
        pL[q] = *(const uint4*)&L[(size_t)(i0+row)*NSEQ + k0 + ssl*8];
        pR[q] = *(const uint4*)&R[(size_t)(j0+row)*NSEQ + k0 + ssl*8];
      }
    }
    #pragma unroll
    for (int kk=0;kk<2;kk++){
      bf16x8 af[2], bfr[2];
      #pragma unroll
      for (int mi=0;mi<2;mi++){
        int row = wi*32 + mi*16 + lr;
        af[mi] = *(const bf16x8*)&ldsL[buf*4096 + row*64 + (((kk*4+lg) ^ (row&7)))*8];
      }
      #pragma unroll
      for (int nj=0;nj<2;nj++){
        int row = wj*32 + nj*16 + lr;
        bfr[nj] = *(const bf16x8*)&ldsR[buf*4096 + row*64 + (((kk*4+lg) ^ (row&7)))*8];
      }
      #pragma unroll
      for (int mi=0;mi<2;mi++)
        #pragma unroll
        for (int nj=0;nj<2;nj++)
          acc[mi][nj] = __builtin_amdgcn_mfma_f32_16x16x32_bf16(af[mi], bfr[nj], acc[mi][nj], 0,0,0);
    }
    if (kt < 7){
      #pragma unroll
      for (int q=0;q<2;q++){
        int row = q*32 + srow;
        int sw = ssl ^ (row & 7);
        *(uint4*)&ldsL[(buf^1)*4096 + row*64 + sw*8] = pL[q];
        *(uint4*)&ldsR[(buf^1)*4096 + row*64 + sw*8] = pR[q];
      }
    }
    __syncthreads();
  }

  // epilogue: bf16 via LDS transpose stage st[64][72]
  const float scale = 0.044194173824159216f;   // 1/sqrt(512)
  u16* st = lds_raw;
  #pragma unroll
  for (int mi=0;mi<2;mi++){
    #pragma unroll
    for (int nj=0;nj<2;nj++){
      int cj = wj*32 + nj*16 + lr;
      #pragma unroll
      for (int g2=0;g2<4;g2++){
        int ri = wi*32 + mi*16 + lg*4 + g2;
        st[ri*72 + cj] = f2bf(acc[mi][nj][g2] * scale);
      }
    }
  }
  __syncthreads();
  {
    int ri = t >> 2, q = t & 3;
    const uint4* src = (const uint4*)&st[ri*72 + q*16];
    uint4* dst = (uint4*)(upd16 + (size_t)c*NN + (size_t)(i0+ri)*NSEQ + j0 + q*16);
    dst[0] = src[0];
    dst[1] = src[1];
  }
}

// ------------- k3a: LN over c of upd16 [c][i*512+j] -> znu [row][c] bf16 --
__global__ __launch_bounds__(256) void k3a_ln(
    const u16* __restrict__ upd16, const float* __restrict__ onw,
    const float* __restrict__ onb, u16* __restrict__ znu)
{
  __shared__ float u[128*129];     // pad-1: LDS writes/reads 2-way (free)
  __shared__ float onw_s[128], onb_s[128];
  const int t = threadIdx.x;
  const int i = blockIdx.x;
  const int j0 = blockIdx.y * 128;

  if (t < 32)      ((float4*)onw_s)[t]    = ((const float4*)onw)[t];
  else if (t < 64) ((float4*)onb_s)[t-32] = ((const float4*)onb)[t-32];

  {
    int cr = t >> 1, h = t & 1;
    const uint4* src = (const uint4*)(upd16 + (size_t)cr*NN + (size_t)i*NSEQ + j0 + h*64);
    float* dst = &u[cr*129 + h*64];
    #pragma unroll
    for (int e=0;e<8;e++){
      uint4 v = src[e];
      const u16* hp = (const u16*)&v;
      #pragma unroll
      for (int p=0;p<8;p++) dst[e*8+p] = bf2f(hp[p]);
    }
  }
  __syncthreads();

  int j = t >> 1, h = t & 1;
  float s = 0.f, sq = 0.f;
  #pragma unroll
  for (int e=0;e<64;e++){
    float v = u[(h*64+e)*129 + j];
    s += v; sq += v*v;
  }
  s += __shfl_xor(s,1); sq += __shfl_xor(sq,1);
  float mu = s * (1.f/128.f);
  float rstd = __builtin_amdgcn_rsqf(sq * (1.f/128.f) - mu*mu + 1e-5f);

  uint32_t pk[32];
  #pragma unroll
  for (int e=0;e<64;e+=2){
    int c0 = h*64 + e;
    float v0 = (u[c0*129 + j]     - mu)*rstd*onw_s[c0]   + onb_s[c0];
    float v1 = (u[(c0+1)*129 + j] - mu)*rstd*onw_s[c0+1] + onb_s[c0+1];
    pk[e>>1] = cvtpk(v0, v1);
  }
  uint4* dst = (uint4*)(znu + ((size_t)i*NSEQ + j0 + j)*CH + h*64);
  #pragma unroll
  for (int e=0;e<8;e++) dst[e] = make_uint4(pk[e*4], pk[e*4+1], pk[e*4+2], pk[e*4+3]);
}

// ------------- k3b: out = (znu @ W_out^T) * og * mask (R1-proven) ---------
__global__ __launch_bounds__(256) void k3b_out(
    const u16* __restrict__ znu, const u16* __restrict__ og,
    const float* __restrict__ pmask, const u16* __restrict__ wts,
    float* __restrict__ out)
{
  __shared__ __align__(16) u16 zn[64][136];
  __shared__ __align__(16) float so[64][132];   // [r][o] fp32 stage
  __shared__ float mask_s[64];
  const int t = threadIdx.x;
  const int row0 = blockIdx.x * 64;

  if (t < 16) ((float4*)mask_s)[t] = ((const float4*)(pmask + row0))[t];
  {
    int r = t >> 2, q = t & 3;
    const uint4* src = (const uint4*)(znu + (size_t)(row0 + r)*CH + q*32);
    uint4* dst = (uint4*)&zn[r][q*32];
    #pragma unroll
    for (int e=0;e<4;e++) dst[e] = src[e];
  }
  __syncthreads();

  const int lane = t & 63, w = t >> 6;
  const int lr = lane & 15, lg = lane >> 4;

  bf16x8 a[4][4];
  #pragma unroll
  for (int mi=0;mi<4;mi++)
    #pragma unroll
    for (int kk=0;kk<4;kk++)
      a[mi][kk] = *(const bf16x8*)&zn[mi*16 + lr][kk*32 + lg*8];

  f32x4 acc[4][2];
  const f32x4 zero4 = {0.f,0.f,0.f,0.f};
  #pragma unroll
  for (int mi=0;mi<4;mi++){ acc[mi][0] = zero4; acc[mi][1] = zero4; }

  #pragma unroll
  for (int kk=0;kk<4;kk++){
    #pragma unroll
    for (int n=0;n<2;n++){
      int o = w*32 + n*16 + lr;
      bf16x8 b = *(const bf16x8*)&wts[5*16384 + o*128 + kk*32 + lg*8];
      #pragma unroll
      for (int mi=0;mi<4;mi++)
        acc[mi][n] = __builtin_amdgcn_mfma_f32_16x16x32_bf16(a[mi][kk], b, acc[mi][n], 0,0,0);
    }
  }
  #pragma unroll
  for (int n=0;n<2;n++){
    int o = w*32 + n*16 + lr;
    #pragma unroll
    for (int mi=0;mi<4;mi++){
      int r0 = mi*16 + lg*4;
      #pragma unroll
      for (int g2=0;g2<4;g2++)
        so[r0+g2][o] = acc[mi][n][g2];
    }
  }
  __syncthreads();
  {
    int r = t >> 2, q = t & 3;
    float m = mask_s[r];
    const u16* ogp = og + (size_t)(row0 + r)*CH + q*32;
    uint4 o4[4];
    #pragma unroll
    for (int e=0;e<4;e++) o4[e] = ((const uint4*)ogp)[e];
    const u16* oh = (const u16*)o4;
    float* dst = out + (size_t)(row0 + r)*CH + q*32;
    #pragma unroll
    for (int e=0;e<8;e++){
      float4 v;
      v.x = so[r][q*32 + e*4+0] * bf2f(oh[e*4+0]) * m;
      v.y = so[r][q*32 + e*4+1] * bf2f(oh[e*4+1]) * m;
      v.z = so[r][q*32 + e*4+2] * bf2f(oh[e*4+2]) * m;
      v.w = so[r][q*32 + e*4+3] * bf2f(oh[e*4+3]) * m;
      ((float4*)dst)[e] = v;
    }
  }
}

// --------------------------- launcher ------------------------------------
extern "C" void kernel_launch(void* const* d_in, const int* in_sizes, int n_in,
                              void* d_out, int out_size, void* d_ws, size_t ws_size,
                              hipStream_t stream)
{
  const float* z       = (const float*)d_in[0];
  const float* pmask   = (const float*)d_in[1];
  const float* lnw     = (const float*)d_in[2];
  const float* lnb     = (const float*)d_in[3];
  const float* W_left  = (const float*)d_in[4];
  const float* W_right = (const float*)d_in[5];
  const float* W_lgate = (const float*)d_in[6];
  const float* b_lgate = (const float*)d_in[7];
  const float* W_rgate = (const float*)d_in[8];
  const float* b_rgate = (const float*)d_in[9];
  const float* onw     = (const float*)d_in[10];
  const float* onb     = (const float*)d_in[11];
  const float* W_out   = (const float*)d_in[12];
  const float* W_ogate = (const float*)d_in[13];
  const float* b_ogate = (const float*)d_in[14];

  const size_t SLOT = 67108864;   // 64 MiB (bf16 [c][i][j] tensor)
  uint8_t* ws = (uint8_t*)d_ws;
  u16* left_t  = (u16*)(ws);               // later reused as znu [row][c]
  u16* right_t = (u16*)(ws + SLOT);
  u16* ogb     = (u16*)(ws + 2*SLOT);      // [row][c]
  u16* wts     = (u16*)(ws + 3*SLOT);
  u16* upd16   = (u16*)d_out;              // d_out doubles as bf16 update scratch

  k0_cvt<<<96, 256, 0, stream>>>(W_left, W_lgate, W_right, W_rgate, W_ogate, W_out, wts);
  k1_proj<<<4096, 256, 0, stream>>>(z, pmask, lnw, lnb, b_lgate, b_rgate, b_ogate,
                                    wts, left_t, right_t, ogb);
  k2_einsum<<<dim3(8,8,128), 256, 0, stream>>>(left_t, right_t, upd16);
  k3a_ln<<<dim3(512,4), 256, 0, stream>>>(upd16, onw, onb, left_t /*znu*/);
  k3b_out<<<4096, 256, 0, stream>>>(left_t, ogb, pmask, wts, (float*)d_out);
}

// Round 4
// 373.280 us; speedup vs baseline: 1.1022x; 1.0018x over previous
//
#include <hip/hip_runtime.h>
#include <stdint.h>

#define NSEQ 512
#define CH   128
#define NN   (NSEQ*NSEQ)   // 262144

typedef unsigned short u16;
typedef __attribute__((ext_vector_type(8))) short bf16x8;  // 8 bf16 = 4 VGPRs
typedef __attribute__((ext_vector_type(4))) float f32x4;

__device__ __forceinline__ u16 f2bf(float x){          // RNE
  uint32_t u = __float_as_uint(x);
  u += 0x7fffu + ((u >> 16) & 1u);
  return (u16)(u >> 16);
}
__device__ __forceinline__ float bf2f(u16 h){
  return __uint_as_float(((uint32_t)h) << 16);
}
__device__ __forceinline__ uint32_t cvtpk(float lo, float hi){  // bf16(lo)|bf16(hi)<<16
  uint32_t r;
  asm volatile("v_cvt_pk_bf16_f32 %0, %1, %2" : "=v"(r) : "v"(lo), "v"(hi));
  return r;
}
__device__ __forceinline__ float sigm(float x){
  return __builtin_amdgcn_rcpf(1.0f + __expf(-x));
}

// left/right tensor layout: [i_z (512)][kblk (8)][c (128)][kin (64)] u16
// offset = i_z*65536 + kblk*8192 + c*64 + kin
// -> k1 block (64 consecutive flat rows = fixed i_z, one kblk) writes each
//    matrix as ONE contiguous 16KB burst (channel-spread, fast drain);
//    k2 tile reads are 128B chunks at 128KB stride (L2-cached, reused 8x).

// ------------- k0: cast 6 weight matrices fp32 -> bf16 -------------
// slot order: 0=W_left 1=W_lgate 2=W_right 3=W_rgate 4=W_ogate 5=W_out
__global__ void k0_cvt(const float* __restrict__ w0, const float* __restrict__ w1,
                       const float* __restrict__ w2, const float* __restrict__ w3,
                       const float* __restrict__ w4, const float* __restrict__ w5,
                       u16* __restrict__ out)
{
  int mat = blockIdx.x >> 4;
  int blk = blockIdx.x & 15;
  const float* src = (mat==0)?w0:(mat==1)?w1:(mat==2)?w2:(mat==3)?w3:(mat==4)?w4:w5;
  int idx = (blk*256 + (int)threadIdx.x) * 4;
  float4 v = *(const float4*)(src + idx);
  uint2 pk;
  pk.x = cvtpk(v.x, v.y);
  pk.y = cvtpk(v.z, v.w);
  *(uint2*)(out + mat*16384 + idx) = pk;
}

// ------------- k1: LN(z) + 5 gated projections ---------------------
// 64 rows/block. left_t/right_t tiled [i][kb][c][kin]; og row-major [row][c].
__global__ __launch_bounds__(256) void k1_proj(
    const float* __restrict__ z, const float* __restrict__ pmask,
    const float* __restrict__ lnw, const float* __restrict__ lnb,
    const float* __restrict__ b_lg, const float* __restrict__ b_rg,
    const float* __restrict__ b_og, const u16* __restrict__ wts,
    u16* __restrict__ left_t, u16* __restrict__ right_t, u16* __restrict__ og)
{
  __shared__ __align__(16) u16 zn[64][136];
  __shared__ __align__(16) u16 stg[128*72];   // [o][r] stage; pass C uses [r][o] 64x136
  __shared__ float lnw_s[128], lnb_s[128], mask_s[64];

  const int t = threadIdx.x;
  const int row0 = blockIdx.x * 64;
  const size_t tile_off = (size_t)(row0 >> 9) * 65536 + (size_t)((row0 >> 6) & 7) * 8192;

  if (t < 32)       ((float4*)lnw_s)[t]     = ((const float4*)lnw)[t];
  else if (t < 64)  ((float4*)lnb_s)[t-32]  = ((const float4*)lnb)[t-32];
  else if (t < 80)  ((float4*)mask_s)[t-64] = ((const float4*)(pmask + row0))[t-64];
  __syncthreads();

  { // --- LayerNorm: thread = (row r, quarter q) covers 32 channels ---
    int r = t >> 2, q = t & 3;
    const float* zp = z + (size_t)(row0 + r) * CH + q * 32;
    float4 v[8];
    #pragma unroll
    for (int e=0;e<8;e++) v[e] = ((const float4*)zp)[e];
    float s = 0.f, sq = 0.f;
    #pragma unroll
    for (int e=0;e<8;e++){
      s  += v[e].x + v[e].y + v[e].z + v[e].w;
      sq += v[e].x*v[e].x + v[e].y*v[e].y + v[e].z*v[e].z + v[e].w*v[e].w;
    }
    s += __shfl_xor(s,1); sq += __shfl_xor(sq,1);
    s += __shfl_xor(s,2); sq += __shfl_xor(sq,2);
    float mu = s * (1.f/128.f);
    float rstd = __builtin_amdgcn_rsqf(sq * (1.f/128.f) - mu*mu + 1e-5f);
    uint32_t pk[16];
    #pragma unroll
    for (int e=0;e<8;e++){
      int c = q*32 + e*4;
      float a0 = (v[e].x - mu)*rstd*lnw_s[c+0] + lnb_s[c+0];
      float a1 = (v[e].y - mu)*rstd*lnw_s[c+1] + lnb_s[c+1];
      float a2 = (v[e].z - mu)*rstd*lnw_s[c+2] + lnb_s[c+2];
      float a3 = (v[e].w - mu)*rstd*lnw_s[c+3] + lnb_s[c+3];
      pk[e*2+0] = cvtpk(a0, a1);
      pk[e*2+1] = cvtpk(a2, a3);
    }
    uint4* dst = (uint4*)&zn[r][q*32];
    #pragma unroll
    for (int e=0;e<4;e++) dst[e] = make_uint4(pk[e*4], pk[e*4+1], pk[e*4+2], pk[e*4+3]);
  }
  __syncthreads();

  const int lane = t & 63;
  const int w = t >> 6;
  const int lr = lane & 15;
  const int lg = lane >> 4;

  bf16x8 a[4][4];
  #pragma unroll
  for (int mi=0;mi<4;mi++)
    #pragma unroll
    for (int kk=0;kk<4;kk++)
      a[mi][kk] = *(const bf16x8*)&zn[mi*16 + lr][kk*32 + lg*8];

  f32x4 acc1[4][2], acc2[4][2];
  const f32x4 zero4 = {0.f,0.f,0.f,0.f};

  // ===== pass A: left = raw * sigmoid(lgate) * mask =====
  #pragma unroll
  for (int mi=0;mi<4;mi++){ acc1[mi][0]=zero4; acc1[mi][1]=zero4; acc2[mi][0]=zero4; acc2[mi][1]=zero4; }
  #pragma unroll
  for (int kk=0;kk<4;kk++){
    #pragma unroll
    for (int n=0;n<2;n++){
      int o = w*32 + n*16 + lr;
      bf16x8 bl = *(const bf16x8*)&wts[0*16384 + o*128 + kk*32 + lg*8];
      bf16x8 bg = *(const bf16x8*)&wts[1*16384 + o*128 + kk*32 + lg*8];
      #pragma unroll
      for (int mi=0;mi<4;mi++){
        acc1[mi][n] = __builtin_amdgcn_mfma_f32_16x16x32_bf16(a[mi][kk], bl, acc1[mi][n], 0,0,0);
        acc2[mi][n] = __builtin_amdgcn_mfma_f32_16x16x32_bf16(a[mi][kk], bg, acc2[mi][n], 0,0,0);
      }
    }
  }
  #pragma unroll
  for (int n=0;n<2;n++){
    int o = w*32 + n*16 + lr;
    float bgv = b_lg[o];
    #pragma unroll
    for (int mi=0;mi<4;mi++){
      int r0 = mi*16 + lg*4;
      float v0 = acc1[mi][n][0] * sigm(acc2[mi][n][0] + bgv) * mask_s[r0+0];
      float v1 = acc1[mi][n][1] * sigm(acc2[mi][n][1] + bgv) * mask_s[r0+1];
      float v2 = acc1[mi][n][2] * sigm(acc2[mi][n][2] + bgv) * mask_s[r0+2];
      float v3 = acc1[mi][n][3] * sigm(acc2[mi][n][3] + bgv) * mask_s[r0+3];
      *(uint2*)&stg[o*72 + r0] = make_uint2(cvtpk(v0,v1), cvtpk(v2,v3));
    }
  }
  __syncthreads();
  { // contiguous 16KB burst: [i][kb][c][kin]
    int o = t >> 1, h = t & 1;
    const uint4* src = (const uint4*)&stg[o*72 + h*32];
    uint4* dst = (uint4*)(left_t + tile_off + o*64 + h*32);
    #pragma unroll
    for (int e=0;e<4;e++) dst[e] = src[e];
  }
  __syncthreads();

  // ===== pass B: right = raw * sigmoid(rgate) * mask =====
  #pragma unroll
  for (int mi=0;mi<4;mi++){ acc1[mi][0]=zero4; acc1[mi][1]=zero4; acc2[mi][0]=zero4; acc2[mi][1]=zero4; }
  #pragma unroll
  for (int kk=0;kk<4;kk++){
    #pragma unroll
    for (int n=0;n<2;n++){
      int o = w*32 + n*16 + lr;
      bf16x8 bl = *(const bf16x8*)&wts[2*16384 + o*128 + kk*32 + lg*8];
      bf16x8 bg = *(const bf16x8*)&wts[3*16384 + o*128 + kk*32 + lg*8];
      #pragma unroll
      for (int mi=0;mi<4;mi++){
        acc1[mi][n] = __builtin_amdgcn_mfma_f32_16x16x32_bf16(a[mi][kk], bl, acc1[mi][n], 0,0,0);
        acc2[mi][n] = __builtin_amdgcn_mfma_f32_16x16x32_bf16(a[mi][kk], bg, acc2[mi][n], 0,0,0);
      }
    }
  }
  #pragma unroll
  for (int n=0;n<2;n++){
    int o = w*32 + n*16 + lr;
    float bgv = b_rg[o];
    #pragma unroll
    for (int mi=0;mi<4;mi++){
      int r0 = mi*16 + lg*4;
      float v0 = acc1[mi][n][0] * sigm(acc2[mi][n][0] + bgv) * mask_s[r0+0];
      float v1 = acc1[mi][n][1] * sigm(acc2[mi][n][1] + bgv) * mask_s[r0+1];
      float v2 = acc1[mi][n][2] * sigm(acc2[mi][n][2] + bgv) * mask_s[r0+2];
      float v3 = acc1[mi][n][3] * sigm(acc2[mi][n][3] + bgv) * mask_s[r0+3];
      *(uint2*)&stg[o*72 + r0] = make_uint2(cvtpk(v0,v1), cvtpk(v2,v3));
    }
  }
  __syncthreads();
  {
    int o = t >> 1, h = t & 1;
    const uint4* src = (const uint4*)&stg[o*72 + h*32];
    uint4* dst = (uint4*)(right_t + tile_off + o*64 + h*32);
    #pragma unroll
    for (int e=0;e<4;e++) dst[e] = src[e];
  }
  __syncthreads();

  // ===== pass C: og = sigmoid(raw + b_og), row-major [row][c] =====
  #pragma unroll
  for (int mi=0;mi<4;mi++){ acc1[mi][0]=zero4; acc1[mi][1]=zero4; }
  #pragma unroll
  for (int kk=0;kk<4;kk++){
    #pragma unroll
    for (int n=0;n<2;n++){
      int o = w*32 + n*16 + lr;
      bf16x8 bo = *(const bf16x8*)&wts[4*16384 + o*128 + kk*32 + lg*8];
      #pragma unroll
      for (int mi=0;mi<4;mi++)
        acc1[mi][n] = __builtin_amdgcn_mfma_f32_16x16x32_bf16(a[mi][kk], bo, acc1[mi][n], 0,0,0);
    }
  }
  #pragma unroll
  for (int n=0;n<2;n++){
    int o = w*32 + n*16 + lr;
    float bgv = b_og[o];
    #pragma unroll
    for (int mi=0;mi<4;mi++){
      int r0 = mi*16 + lg*4;
      #pragma unroll
      for (int g2=0;g2<4;g2++)
        stg[(r0+g2)*136 + o] = f2bf(sigm(acc1[mi][n][g2] + bgv));   // [r][o] view
    }
  }
  __syncthreads();
  {
    int r = t >> 2, q = t & 3;
    const uint4* src = (const uint4*)&stg[r*136 + q*32];
    uint4* dst = (uint4*)(og + (size_t)(row0 + r)*CH + q*32);
    #pragma unroll
    for (int e=0;e<4;e++) dst[e] = src[e];
  }
}

// ------------- k2: per-channel 64x64x512 GEMM, bf16 output ----------------
// L/R layout [i][kb][c][kin]: tile row (i0+row, k-tile kt) = 128B at
// (i0+row)*65536 + kt*8192 + c*64.
__global__ __launch_bounds__(256) void k2_einsum(
    const u16* __restrict__ left_t, const u16* __restrict__ right_t,
    u16* __restrict__ upd16)
{
  __shared__ __align__(16) u16 lds_raw[16384];   // 32KB: L dbuf | R dbuf; reused as stage
  const int t = threadIdx.x;
  const int lane = t & 63, w = t >> 6;
  const int wi = w >> 1, wj = w & 1;
  const int lr = lane & 15, lg = lane >> 4;
  const int i0 = blockIdx.x * 64, j0 = blockIdx.y * 64;
  const int c  = blockIdx.z;

  const int srow = t >> 3;
  const int ssl  = t & 7;
  const size_t cofs = (size_t)c*64 + ssl*8;

  f32x4 acc[2][2];
  const f32x4 zero4 = {0.f,0.f,0.f,0.f};
  acc[0][0]=zero4; acc[0][1]=zero4; acc[1][0]=zero4; acc[1][1]=zero4;

  u16* ldsL = lds_raw;          // [2][4096]
  u16* ldsR = lds_raw + 8192;   // [2][4096]

  {
    #pragma unroll
    for (int q=0;q<2;q++){
      int row = q*32 + srow;
      int sw = ssl ^ (row & 7);
      uint4 vL = *(const uint4*)&left_t [(size_t)(i0+row)*65536 + cofs];
      uint4 vR = *(const uint4*)&right_t[(size_t)(j0+row)*65536 + cofs];
      *(uint4*)&ldsL[row*64 + sw*8] = vL;
      *(uint4*)&ldsR[row*64 + sw*8] = vR;
    }
  }
  __syncthreads();

  for (int kt=0; kt<8; kt++){
    const int buf = kt & 1;
    uint4 pL[2], pR[2];
    if (kt < 7){
      size_t ko = (size_t)(kt+1)*8192 + cofs;
      #pragma unroll
      for (int q=0;q<2;q++){
        int row = q*32 + srow;
        pL[q] = *(const uint4*)&left_t [(size_t)(i0+row)*65536 + ko];
        pR[q] = *(const uint4*)&right_t[(size_t)(j0+row)*65536 + ko];
      }
    }
    #pragma unroll
    for (int kk=0;kk<2;kk++){
      bf16x8 af[2], bfr[2];
      #pragma unroll
      for (int mi=0;mi<2;mi++){
        int row = wi*32 + mi*16 + lr;
        af[mi] = *(const bf16x8*)&ldsL[buf*4096 + row*64 + (((kk*4+lg) ^ (row&7)))*8];
      }
      #pragma unroll
      for (int nj=0;nj<2;nj++){
        int row = wj*32 + nj*16 + lr;
        bfr[nj] = *(const bf16x8*)&ldsR[buf*4096 + row*64 + (((kk*4+lg) ^ (row&7)))*8];
      }
      #pragma unroll
      for (int mi=0;mi<2;mi++)
        #pragma unroll
        for (int nj=0;nj<2;nj++)
          acc[mi][nj] = __builtin_amdgcn_mfma_f32_16x16x32_bf16(af[mi], bfr[nj], acc[mi][nj], 0,0,0);
    }
    if (kt < 7){
      #pragma unroll
      for (int q=0;q<2;q++){
        int row = q*32 + srow;
        int sw = ssl ^ (row & 7);
        *(uint4*)&ldsL[(buf^1)*4096 + row*64 + sw*8] = pL[q];
        *(uint4*)&ldsR[(buf^1)*4096 + row*64 + sw*8] = pR[q];
      }
    }
    __syncthreads();
  }

  // epilogue: bf16 via LDS transpose stage st[64][72]
  const float scale = 0.044194173824159216f;   // 1/sqrt(512)
  u16* st = lds_raw;
  #pragma unroll
  for (int mi=0;mi<2;mi++){
    #pragma unroll
    for (int nj=0;nj<2;nj++){
      int cj = wj*32 + nj*16 + lr;
      #pragma unroll
      for (int g2=0;g2<4;g2++){
        int ri = wi*32 + mi*16 + lg*4 + g2;
        st[ri*72 + cj] = f2bf(acc[mi][nj][g2] * scale);
      }
    }
  }
  __syncthreads();
  {
    int ri = t >> 2, q = t & 3;
    const uint4* src = (const uint4*)&st[ri*72 + q*16];
    uint4* dst = (uint4*)(upd16 + (size_t)c*NN + (size_t)(i0+ri)*NSEQ + j0 + q*16);
    dst[0] = src[0];
    dst[1] = src[1];
  }
}

// ------------- k3a: LN over c of upd16 [c][i*512+j] -> znu [row][c] bf16 --
__global__ __launch_bounds__(256) void k3a_ln(
    const u16* __restrict__ upd16, const float* __restrict__ onw,
    const float* __restrict__ onb, u16* __restrict__ znu)
{
  __shared__ float u[128*129];     // pad-1: LDS writes/reads 2-way (free)
  __shared__ float onw_s[128], onb_s[128];
  const int t = threadIdx.x;
  const int i = blockIdx.x;
  const int j0 = blockIdx.y * 128;

  if (t < 32)      ((float4*)onw_s)[t]    = ((const float4*)onw)[t];
  else if (t < 64) ((float4*)onb_s)[t-32] = ((const float4*)onb)[t-32];

  {
    int cr = t >> 1, h = t & 1;
    const uint4* src = (const uint4*)(upd16 + (size_t)cr*NN + (size_t)i*NSEQ + j0 + h*64);
    float* dst = &u[cr*129 + h*64];
    #pragma unroll
    for (int e=0;e<8;e++){
      uint4 v = src[e];
      const u16* hp = (const u16*)&v;
      #pragma unroll
      for (int p=0;p<8;p++) dst[e*8+p] = bf2f(hp[p]);
    }
  }
  __syncthreads();

  int j = t >> 1, h = t & 1;
  float s = 0.f, sq = 0.f;
  #pragma unroll
  for (int e=0;e<64;e++){
    float v = u[(h*64+e)*129 + j];
    s += v; sq += v*v;
  }
  s += __shfl_xor(s,1); sq += __shfl_xor(sq,1);
  float mu = s * (1.f/128.f);
  float rstd = __builtin_amdgcn_rsqf(sq * (1.f/128.f) - mu*mu + 1e-5f);

  uint32_t pk[32];
  #pragma unroll
  for (int e=0;e<64;e+=2){
    int c0 = h*64 + e;
    float v0 = (u[c0*129 + j]     - mu)*rstd*onw_s[c0]   + onb_s[c0];
    float v1 = (u[(c0+1)*129 + j] - mu)*rstd*onw_s[c0+1] + onb_s[c0+1];
    pk[e>>1] = cvtpk(v0, v1);
  }
  uint4* dst = (uint4*)(znu + ((size_t)i*NSEQ + j0 + j)*CH + h*64);
  #pragma unroll
  for (int e=0;e<8;e++) dst[e] = make_uint4(pk[e*4], pk[e*4+1], pk[e*4+2], pk[e*4+3]);
}

// ------------- k3b: out = (znu @ W_out^T) * og * mask ---------------------
__global__ __launch_bounds__(256) void k3b_out(
    const u16* __restrict__ znu, const u16* __restrict__ og,
    const float* __restrict__ pmask, const u16* __restrict__ wts,
    float* __restrict__ out)
{
  __shared__ __align__(16) u16 zn[64][136];
  __shared__ __align__(16) float so[64][132];   // [r][o] fp32 stage
  __shared__ float mask_s[64];
  const int t = threadIdx.x;
  const int row0 = blockIdx.x * 64;

  if (t < 16) ((float4*)mask_s)[t] = ((const float4*)(pmask + row0))[t];
  {
    int r = t >> 2, q = t & 3;
    const uint4* src = (const uint4*)(znu + (size_t)(row0 + r)*CH + q*32);
    uint4* dst = (uint4*)&zn[r][q*32];
    #pragma unroll
    for (int e=0;e<4;e++) dst[e] = src[e];
  }
  __syncthreads();

  const int lane = t & 63, w = t >> 6;
  const int lr = lane & 15, lg = lane >> 4;

  bf16x8 a[4][4];
  #pragma unroll
  for (int mi=0;mi<4;mi++)
    #pragma unroll
    for (int kk=0;kk<4;kk++)
      a[mi][kk] = *(const bf16x8*)&zn[mi*16 + lr][kk*32 + lg*8];

  f32x4 acc[4][2];
  const f32x4 zero4 = {0.f,0.f,0.f,0.f};
  #pragma unroll
  for (int mi=0;mi<4;mi++){ acc[mi][0] = zero4; acc[mi][1] = zero4; }

  #pragma unroll
  for (int kk=0;kk<4;kk++){
    #pragma unroll
    for (int n=0;n<2;n++){
      int o = w*32 + n*16 + lr;
      bf16x8 b = *(const bf16x8*)&wts[5*16384 + o*128 + kk*32 + lg*8];
      #pragma unroll
      for (int mi=0;mi<4;mi++)
        acc[mi][n] = __builtin_amdgcn_mfma_f32_16x16x32_bf16(a[mi][kk], b, acc[mi][n], 0,0,0);
    }
  }
  #pragma unroll
  for (int n=0;n<2;n++){
    int o = w*32 + n*16 + lr;
    #pragma unroll
    for (int mi=0;mi<4;mi++){
      int r0 = mi*16 + lg*4;
      #pragma unroll
      for (int g2=0;g2<4;g2++)
        so[r0+g2][o] = acc[mi][n][g2];
    }
  }
  __syncthreads();
  {
    int r = t >> 2, q = t & 3;
    float m = mask_s[r];
    const u16* ogp = og + (size_t)(row0 + r)*CH + q*32;
    uint4 o4[4];
    #pragma unroll
    for (int e=0;e<4;e++) o4[e] = ((const uint4*)ogp)[e];
    const u16* oh = (const u16*)o4;
    float* dst = out + (size_t)(row0 + r)*CH + q*32;
    #pragma unroll
    for (int e=0;e<8;e++){
      float4 v;
      v.x = so[r][q*32 + e*4+0] * bf2f(oh[e*4+0]) * m;
      v.y = so[r][q*32 + e*4+1] * bf2f(oh[e*4+1]) * m;
      v.z = so[r][q*32 + e*4+2] * bf2f(oh[e*4+2]) * m;
      v.w = so[r][q*32 + e*4+3] * bf2f(oh[e*4+3]) * m;
      ((float4*)dst)[e] = v;
    }
  }
}

// --------------------------- launcher ------------------------------------
extern "C" void kernel_launch(void* const* d_in, const int* in_sizes, int n_in,
                              void* d_out, int out_size, void* d_ws, size_t ws_size,
                              hipStream_t stream)
{
  const float* z       = (const float*)d_in[0];
  const float* pmask   = (const float*)d_in[1];
  const float* lnw     = (const float*)d_in[2];
  const float* lnb     = (const float*)d_in[3];
  const float* W_left  = (const float*)d_in[4];
  const float* W_right = (const float*)d_in[5];
  const float* W_lgate = (const float*)d_in[6];
  const float* b_lgate = (const float*)d_in[7];
  const float* W_rgate = (const float*)d_in[8];
  const float* b_rgate = (const float*)d_in[9];
  const float* onw     = (const float*)d_in[10];
  const float* onb     = (const float*)d_in[11];
  const float* W_out   = (const float*)d_in[12];
  const float* W_ogate = (const float*)d_in[13];
  const float* b_ogate = (const float*)d_in[14];

  const size_t SLOT = 67108864;   // 64 MiB (bf16 [i][kb][c][kin] tensor)
  uint8_t* ws = (uint8_t*)d_ws;
  u16* left_t  = (u16*)(ws);               // later reused as znu [row][c]
  u16* right_t = (u16*)(ws + SLOT);
  u16* ogb     = (u16*)(ws + 2*SLOT);      // [row][c]
  u16* wts     = (u16*)(ws + 3*SLOT);
  u16* upd16   = (u16*)d_out;              // d_out doubles as bf16 update scratch

  k0_cvt<<<96, 256, 0, stream>>>(W_left, W_lgate, W_right, W_rgate, W_ogate, W_out, wts);
  k1_proj<<<4096, 256, 0, stream>>>(z, pmask, lnw, lnb, b_lgate, b_rgate, b_ogate,
                                    wts, left_t, right_t, ogb);
  k2_einsum<<<dim3(8,8,128), 256, 0, stream>>>(left_t, right_t, upd16);
  k3a_ln<<<dim3(512,4), 256, 0, stream>>>(upd16, onw, onb, left_t /*znu*/);
  k3b_out<<<4096, 256, 0, stream>>>(left_t, ogb, pmask, wts, (float*)d_out);
}

// Round 5
// 362.241 us; speedup vs baseline: 1.1358x; 1.0305x over previous
//
#include <hip/hip_runtime.h>
#include <stdint.h>

#define NSEQ 512
#define CH   128
#define NN   (NSEQ*NSEQ)   // 262144

typedef unsigned short u16;
typedef __attribute__((ext_vector_type(8))) short bf16x8;  // 8 bf16 = 4 VGPRs
typedef __attribute__((ext_vector_type(4))) float f32x4;

__device__ __forceinline__ u16 f2bf(float x){          // RNE
  uint32_t u = __float_as_uint(x);
  u += 0x7fffu + ((u >> 16) & 1u);
  return (u16)(u >> 16);
}
__device__ __forceinline__ float bf2f(u16 h){
  return __uint_as_float(((uint32_t)h) << 16);
}
__device__ __forceinline__ uint32_t cvtpk(float lo, float hi){  // bf16(lo)|bf16(hi)<<16
  uint32_t r;
  asm volatile("v_cvt_pk_bf16_f32 %0, %1, %2" : "=v"(r) : "v"(lo), "v"(hi));
  return r;
}
__device__ __forceinline__ float sigm(float x){
  return __builtin_amdgcn_rcpf(1.0f + __expf(-x));
}

// left/right tensor layout: [i (512)][kblk (8)][c (128)][kin (64)] u16
// offset = i*65536 + kblk*8192 + c*64 + kin   (flat row n = i*512 + kblk*64 + kin)

// ------------- k0: cast 6 weight matrices fp32 -> bf16 -------------
// slot order: 0=W_left 1=W_lgate 2=W_right 3=W_rgate 4=W_ogate 5=W_out
__global__ void k0_cvt(const float* __restrict__ w0, const float* __restrict__ w1,
                       const float* __restrict__ w2, const float* __restrict__ w3,
                       const float* __restrict__ w4, const float* __restrict__ w5,
                       u16* __restrict__ out)
{
  int mat = blockIdx.x >> 4;
  int blk = blockIdx.x & 15;
  const float* src = (mat==0)?w0:(mat==1)?w1:(mat==2)?w2:(mat==3)?w3:(mat==4)?w4:w5;
  int idx = (blk*256 + (int)threadIdx.x) * 4;
  float4 v = *(const float4*)(src + idx);
  uint2 pk;
  pk.x = cvtpk(v.x, v.y);
  pk.y = cvtpk(v.z, v.w);
  *(uint2*)(out + mat*16384 + idx) = pk;
}

// ------------- k1a: LN(z) -> znS bf16 [row][c], pure streaming ------------
__global__ __launch_bounds__(256) void k1a_ln(
    const float* __restrict__ z, const float* __restrict__ lnw,
    const float* __restrict__ lnb, u16* __restrict__ znS)
{
  __shared__ float lnw_s[128], lnb_s[128];
  const int t = threadIdx.x;
  const int row0 = blockIdx.x * 64;
  if (t < 32)      ((float4*)lnw_s)[t]    = ((const float4*)lnw)[t];
  else if (t < 64) ((float4*)lnb_s)[t-32] = ((const float4*)lnb)[t-32];
  __syncthreads();

  int r = t >> 2, q = t & 3;
  const float* zp = z + (size_t)(row0 + r) * CH + q * 32;
  float4 v[8];
  #pragma unroll
  for (int e=0;e<8;e++) v[e] = ((const float4*)zp)[e];
  float s = 0.f, sq = 0.f;
  #pragma unroll
  for (int e=0;e<8;e++){
    s  += v[e].x + v[e].y + v[e].z + v[e].w;
    sq += v[e].x*v[e].x + v[e].y*v[e].y + v[e].z*v[e].z + v[e].w*v[e].w;
  }
  s += __shfl_xor(s,1); sq += __shfl_xor(sq,1);
  s += __shfl_xor(s,2); sq += __shfl_xor(sq,2);
  float mu = s * (1.f/128.f);
  float rstd = __builtin_amdgcn_rsqf(sq * (1.f/128.f) - mu*mu + 1e-5f);
  uint32_t pk[16];
  #pragma unroll
  for (int e=0;e<8;e++){
    int c = q*32 + e*4;
    float a0 = (v[e].x - mu)*rstd*lnw_s[c+0] + lnb_s[c+0];
    float a1 = (v[e].y - mu)*rstd*lnw_s[c+1] + lnb_s[c+1];
    float a2 = (v[e].z - mu)*rstd*lnw_s[c+2] + lnb_s[c+2];
    float a3 = (v[e].w - mu)*rstd*lnw_s[c+3] + lnb_s[c+3];
    pk[e*2+0] = cvtpk(a0, a1);
    pk[e*2+1] = cvtpk(a2, a3);
  }
  uint4* dst = (uint4*)(znS + (size_t)(row0 + r)*CH + q*32);
  #pragma unroll
  for (int e=0;e<4;e++) dst[e] = make_uint4(pk[e*4], pk[e*4+1], pk[e*4+2], pk[e*4+3]);
}

// ------------- k1b: 2 gated projections, barrier-free main body -----------
__global__ __launch_bounds__(256) void k1b_proj(
    const u16* __restrict__ znS, const float* __restrict__ pmask,
    const float* __restrict__ b_lg, const float* __restrict__ b_rg,
    const u16* __restrict__ wts,
    u16* __restrict__ left_t, u16* __restrict__ right_t)
{
  __shared__ __align__(16) u16 zn[64][136];
  __shared__ float mask_s[64];
  const int t = threadIdx.x;
  const int row0 = blockIdx.x * 64;
  const size_t tile_off = (size_t)(row0 >> 9)*65536 + (size_t)((row0 >> 6) & 7)*8192;

  // stage znorm tile (16KB) reg->LDS, linear->padded rows
  #pragma unroll
  for (int k=0;k<4;k++){
    uint4 v = *(const uint4*)(znS + (size_t)row0*CH + k*2048 + t*8);
    int r = k*16 + (t>>4), g = t & 15;
    *(uint4*)&zn[r][g*8] = v;
  }
  if (t < 16) ((float4*)mask_s)[t] = ((const float4*)(pmask + row0))[t];
  __syncthreads();   // the ONLY barrier

  const int lane = t & 63;
  const int w = t >> 6;
  const int lr = lane & 15;
  const int lg = lane >> 4;

  bf16x8 a[4][4];
  #pragma unroll
  for (int mi=0;mi<4;mi++)
    #pragma unroll
    for (int kk=0;kk<4;kk++)
      a[mi][kk] = *(const bf16x8*)&zn[mi*16 + lr][kk*32 + lg*8];

  f32x4 acc1[4][2], acc2[4][2];
  const f32x4 zero4 = {0.f,0.f,0.f,0.f};

  // ===== pass A: left = raw * sigmoid(lgate) * mask -> direct stores =====
  #pragma unroll
  for (int mi=0;mi<4;mi++){ acc1[mi][0]=zero4; acc1[mi][1]=zero4; acc2[mi][0]=zero4; acc2[mi][1]=zero4; }
  #pragma unroll
  for (int kk=0;kk<4;kk++){
    #pragma unroll
    for (int n=0;n<2;n++){
      int o = w*32 + n*16 + lr;
      bf16x8 bl = *(const bf16x8*)&wts[0*16384 + o*128 + kk*32 + lg*8];
      bf16x8 bg = *(const bf16x8*)&wts[1*16384 + o*128 + kk*32 + lg*8];
      #pragma unroll
      for (int mi=0;mi<4;mi++){
        acc1[mi][n] = __builtin_amdgcn_mfma_f32_16x16x32_bf16(a[mi][kk], bl, acc1[mi][n], 0,0,0);
        acc2[mi][n] = __builtin_amdgcn_mfma_f32_16x16x32_bf16(a[mi][kk], bg, acc2[mi][n], 0,0,0);
      }
    }
  }
  #pragma unroll
  for (int n=0;n<2;n++){
    int o = w*32 + n*16 + lr;
    float bgv = b_lg[o];
    #pragma unroll
    for (int mi=0;mi<4;mi++){
      int r0 = mi*16 + lg*4;
      float v0 = acc1[mi][n][0] * sigm(acc2[mi][n][0] + bgv) * mask_s[r0+0];
      float v1 = acc1[mi][n][1] * sigm(acc2[mi][n][1] + bgv) * mask_s[r0+1];
      float v2 = acc1[mi][n][2] * sigm(acc2[mi][n][2] + bgv) * mask_s[r0+2];
      float v3 = acc1[mi][n][3] * sigm(acc2[mi][n][3] + bgv) * mask_s[r0+3];
      *(uint2*)(left_t + tile_off + o*64 + r0) = make_uint2(cvtpk(v0,v1), cvtpk(v2,v3));
    }
  }

  // ===== pass B: right = raw * sigmoid(rgate) * mask -> direct stores =====
  #pragma unroll
  for (int mi=0;mi<4;mi++){ acc1[mi][0]=zero4; acc1[mi][1]=zero4; acc2[mi][0]=zero4; acc2[mi][1]=zero4; }
  #pragma unroll
  for (int kk=0;kk<4;kk++){
    #pragma unroll
    for (int n=0;n<2;n++){
      int o = w*32 + n*16 + lr;
      bf16x8 bl = *(const bf16x8*)&wts[2*16384 + o*128 + kk*32 + lg*8];
      bf16x8 bg = *(const bf16x8*)&wts[3*16384 + o*128 + kk*32 + lg*8];
      #pragma unroll
      for (int mi=0;mi<4;mi++){
        acc1[mi][n] = __builtin_amdgcn_mfma_f32_16x16x32_bf16(a[mi][kk], bl, acc1[mi][n], 0,0,0);
        acc2[mi][n] = __builtin_amdgcn_mfma_f32_16x16x32_bf16(a[mi][kk], bg, acc2[mi][n], 0,0,0);
      }
    }
  }
  #pragma unroll
  for (int n=0;n<2;n++){
    int o = w*32 + n*16 + lr;
    float bgv = b_rg[o];
    #pragma unroll
    for (int mi=0;mi<4;mi++){
      int r0 = mi*16 + lg*4;
      float v0 = acc1[mi][n][0] * sigm(acc2[mi][n][0] + bgv) * mask_s[r0+0];
      float v1 = acc1[mi][n][1] * sigm(acc2[mi][n][1] + bgv) * mask_s[r0+1];
      float v2 = acc1[mi][n][2] * sigm(acc2[mi][n][2] + bgv) * mask_s[r0+2];
      float v3 = acc1[mi][n][3] * sigm(acc2[mi][n][3] + bgv) * mask_s[r0+3];
      *(uint2*)(right_t + tile_off + o*64 + r0) = make_uint2(cvtpk(v0,v1), cvtpk(v2,v3));
    }
  }
}

// ------------- k2: per-channel 64x64x512 GEMM, bf16 output (unchanged) ----
__global__ __launch_bounds__(256) void k2_einsum(
    const u16* __restrict__ left_t, const u16* __restrict__ right_t,
    u16* __restrict__ upd16)
{
  __shared__ __align__(16) u16 lds_raw[16384];
  const int t = threadIdx.x;
  const int lane = t & 63, w = t >> 6;
  const int wi = w >> 1, wj = w & 1;
  const int lr = lane & 15, lg = lane >> 4;
  const int i0 = blockIdx.x * 64, j0 = blockIdx.y * 64;
  const int c  = blockIdx.z;

  const int srow = t >> 3;
  const int ssl  = t & 7;
  const size_t cofs = (size_t)c*64 + ssl*8;

  f32x4 acc[2][2];
  const f32x4 zero4 = {0.f,0.f,0.f,0.f};
  acc[0][0]=zero4; acc[0][1]=zero4; acc[1][0]=zero4; acc[1][1]=zero4;

  u16* ldsL = lds_raw;
  u16* ldsR = lds_raw + 8192;

  {
    #pragma unroll
    for (int q=0;q<2;q++){
      int row = q*32 + srow;
      int sw = ssl ^ (row & 7);
      uint4 vL = *(const uint4*)&left_t [(size_t)(i0+row)*65536 + cofs];
      uint4 vR = *(const uint4*)&right_t[(size_t)(j0+row)*65536 + cofs];
      *(uint4*)&ldsL[row*64 + sw*8] = vL;
      *(uint4*)&ldsR[row*64 + sw*8] = vR;
    }
  }
  __syncthreads();

  for (int kt=0; kt<8; kt++){
    const int buf = kt & 1;
    uint4 pL[2], pR[2];
    if (kt < 7){
      size_t ko = (size_t)(kt+1)*8192 + cofs;
      #pragma unroll
      for (int q=0;q<2;q++){
        int row = q*32 + srow;
        pL[q] = *(const uint4*)&left_t [(size_t)(i0+row)*65536 + ko];
        pR[q] = *(const uint4*)&right_t[(size_t)(j0+row)*65536 + ko];
      }
    }
    #pragma unroll
    for (int kk=0;kk<2;kk++){
      bf16x8 af[2], bfr[2];
      #pragma unroll
      for (int mi=0;mi<2;mi++){
        int row = wi*32 + mi*16 + lr;
        af[mi] = *(const bf16x8*)&ldsL[buf*4096 + row*64 + (((kk*4+lg) ^ (row&7)))*8];
      }
      #pragma unroll
      for (int nj=0;nj<2;nj++){
        int row = wj*32 + nj*16 + lr;
        bfr[nj] = *(const bf16x8*)&ldsR[buf*4096 + row*64 + (((kk*4+lg) ^ (row&7)))*8];
      }
      #pragma unroll
      for (int mi=0;mi<2;mi++)
        #pragma unroll
        for (int nj=0;nj<2;nj++)
          acc[mi][nj] = __builtin_amdgcn_mfma_f32_16x16x32_bf16(af[mi], bfr[nj], acc[mi][nj], 0,0,0);
    }
    if (kt < 7){
      #pragma unroll
      for (int q=0;q<2;q++){
        int row = q*32 + srow;
        int sw = ssl ^ (row & 7);
        *(uint4*)&ldsL[(buf^1)*4096 + row*64 + sw*8] = pL[q];
        *(uint4*)&ldsR[(buf^1)*4096 + row*64 + sw*8] = pR[q];
      }
    }
    __syncthreads();
  }

  const float scale = 0.044194173824159216f;   // 1/sqrt(512)
  u16* st = lds_raw;
  #pragma unroll
  for (int mi=0;mi<2;mi++){
    #pragma unroll
    for (int nj=0;nj<2;nj++){
      int cj = wj*32 + nj*16 + lr;
      #pragma unroll
      for (int g2=0;g2<4;g2++){
        int ri = wi*32 + mi*16 + lg*4 + g2;
        st[ri*72 + cj] = f2bf(acc[mi][nj][g2] * scale);
      }
    }
  }
  __syncthreads();
  {
    int ri = t >> 2, q = t & 3;
    const uint4* src = (const uint4*)&st[ri*72 + q*16];
    uint4* dst = (uint4*)(upd16 + (size_t)c*NN + (size_t)(i0+ri)*NSEQ + j0 + q*16);
    dst[0] = src[0];
    dst[1] = src[1];
  }
}

// ------------- k3a: LN over c of upd16 [c][i*512+j] -> znu [row][c] bf16 --
__global__ __launch_bounds__(256) void k3a_ln(
    const u16* __restrict__ upd16, const float* __restrict__ onw,
    const float* __restrict__ onb, u16* __restrict__ znu)
{
  __shared__ float u[128*129];
  __shared__ float onw_s[128], onb_s[128];
  const int t = threadIdx.x;
  const int i = blockIdx.x;
  const int j0 = blockIdx.y * 128;

  if (t < 32)      ((float4*)onw_s)[t]    = ((const float4*)onw)[t];
  else if (t < 64) ((float4*)onb_s)[t-32] = ((const float4*)onb)[t-32];

  {
    int cr = t >> 1, h = t & 1;
    const uint4* src = (const uint4*)(upd16 + (size_t)cr*NN + (size_t)i*NSEQ + j0 + h*64);
    float* dst = &u[cr*129 + h*64];
    #pragma unroll
    for (int e=0;e<8;e++){
      uint4 v = src[e];
      const u16* hp = (const u16*)&v;
      #pragma unroll
      for (int p=0;p<8;p++) dst[e*8+p] = bf2f(hp[p]);
    }
  }
  __syncthreads();

  int j = t >> 1, h = t & 1;
  float s = 0.f, sq = 0.f;
  #pragma unroll
  for (int e=0;e<64;e++){
    float v = u[(h*64+e)*129 + j];
    s += v; sq += v*v;
  }
  s += __shfl_xor(s,1); sq += __shfl_xor(sq,1);
  float mu = s * (1.f/128.f);
  float rstd = __builtin_amdgcn_rsqf(sq * (1.f/128.f) - mu*mu + 1e-5f);

  uint32_t pk[32];
  #pragma unroll
  for (int e=0;e<64;e+=2){
    int c0 = h*64 + e;
    float v0 = (u[c0*129 + j]     - mu)*rstd*onw_s[c0]   + onb_s[c0];
    float v1 = (u[(c0+1)*129 + j] - mu)*rstd*onw_s[c0+1] + onb_s[c0+1];
    pk[e>>1] = cvtpk(v0, v1);
  }
  uint4* dst = (uint4*)(znu + ((size_t)i*NSEQ + j0 + j)*CH + h*64);
  #pragma unroll
  for (int e=0;e<8;e++) dst[e] = make_uint4(pk[e*4], pk[e*4+1], pk[e*4+2], pk[e*4+3]);
}

// ------------- k3b: out = (LN'd-update @ W_out^T) * sigm(zn@W_og^T+b) * mask
__global__ __launch_bounds__(256) void k3b_out(
    const u16* __restrict__ znu, const u16* __restrict__ znS,
    const float* __restrict__ pmask, const float* __restrict__ b_og,
    const u16* __restrict__ wts, float* __restrict__ out)
{
  __shared__ __align__(16) u16 uL[64][136];
  __shared__ __align__(16) u16 zL[64][136];
  __shared__ float mask_s[64];
  const int t = threadIdx.x;
  const int row0 = blockIdx.x * 64;

  #pragma unroll
  for (int k=0;k<4;k++){
    uint4 vu = *(const uint4*)(znu + (size_t)row0*CH + k*2048 + t*8);
    uint4 vz = *(const uint4*)(znS + (size_t)row0*CH + k*2048 + t*8);
    int r = k*16 + (t>>4), g = t & 15;
    *(uint4*)&uL[r][g*8] = vu;
    *(uint4*)&zL[r][g*8] = vz;
  }
  if (t < 16) ((float4*)mask_s)[t] = ((const float4*)(pmask + row0))[t];
  __syncthreads();

  const int lane = t & 63, w = t >> 6;
  const int lr = lane & 15, lg = lane >> 4;

  f32x4 acc_o[4][2], acc_g[4][2];
  const f32x4 zero4 = {0.f,0.f,0.f,0.f};
  #pragma unroll
  for (int mi=0;mi<4;mi++){ acc_o[mi][0]=zero4; acc_o[mi][1]=zero4; acc_g[mi][0]=zero4; acc_g[mi][1]=zero4; }

  // GEMM1: znu @ W_out^T
  #pragma unroll
  for (int kk=0;kk<4;kk++){
    bf16x8 a[4];
    #pragma unroll
    for (int mi=0;mi<4;mi++)
      a[mi] = *(const bf16x8*)&uL[mi*16 + lr][kk*32 + lg*8];
    #pragma unroll
    for (int n=0;n<2;n++){
      int o = w*32 + n*16 + lr;
      bf16x8 b = *(const bf16x8*)&wts[5*16384 + o*128 + kk*32 + lg*8];
      #pragma unroll
      for (int mi=0;mi<4;mi++)
        acc_o[mi][n] = __builtin_amdgcn_mfma_f32_16x16x32_bf16(a[mi], b, acc_o[mi][n], 0,0,0);
    }
  }
  // GEMM2: znS @ W_ogate^T
  #pragma unroll
  for (int kk=0;kk<4;kk++){
    bf16x8 a[4];
    #pragma unroll
    for (int mi=0;mi<4;mi++)
      a[mi] = *(const bf16x8*)&zL[mi*16 + lr][kk*32 + lg*8];
    #pragma unroll
    for (int n=0;n<2;n++){
      int o = w*32 + n*16 + lr;
      bf16x8 b = *(const bf16x8*)&wts[4*16384 + o*128 + kk*32 + lg*8];
      #pragma unroll
      for (int mi=0;mi<4;mi++)
        acc_g[mi][n] = __builtin_amdgcn_mfma_f32_16x16x32_bf16(a[mi], b, acc_g[mi][n], 0,0,0);
    }
  }

  // combine in-register (identical C-layouts) + direct fp32 stores
  #pragma unroll
  for (int n=0;n<2;n++){
    int o = w*32 + n*16 + lr;
    float bgv = b_og[o];
    #pragma unroll
    for (int mi=0;mi<4;mi++){
      #pragma unroll
      for (int g2=0;g2<4;g2++){
        int r = mi*16 + lg*4 + g2;
        float val = acc_o[mi][n][g2] * sigm(acc_g[mi][n][g2] + bgv) * mask_s[r];
        out[(size_t)(row0 + r)*CH + o] = val;
      }
    }
  }
}

// --------------------------- launcher ------------------------------------
extern "C" void kernel_launch(void* const* d_in, const int* in_sizes, int n_in,
                              void* d_out, int out_size, void* d_ws, size_t ws_size,
                              hipStream_t stream)
{
  const float* z       = (const float*)d_in[0];
  const float* pmask   = (const float*)d_in[1];
  const float* lnw     = (const float*)d_in[2];
  const float* lnb     = (const float*)d_in[3];
  const float* W_left  = (const float*)d_in[4];
  const float* W_right = (const float*)d_in[5];
  const float* W_lgate = (const float*)d_in[6];
  const float* b_lgate = (const float*)d_in[7];
  const float* W_rgate = (const float*)d_in[8];
  const float* b_rgate = (const float*)d_in[9];
  const float* onw     = (const float*)d_in[10];
  const float* onb     = (const float*)d_in[11];
  const float* W_out   = (const float*)d_in[12];
  const float* W_ogate = (const float*)d_in[13];
  const float* b_ogate = (const float*)d_in[14];

  const size_t SLOT = 67108864;   // 64 MiB
  uint8_t* ws = (uint8_t*)d_ws;
  u16* left_t  = (u16*)(ws);               // [i][kb][c][kin]; reused as znu after k2
  u16* right_t = (u16*)(ws + SLOT);
  u16* znS     = (u16*)(ws + 2*SLOT);      // LN(z) bf16 [row][c]
  u16* wts     = (u16*)(ws + 3*SLOT);
  u16* upd16   = (u16*)d_out;              // d_out doubles as bf16 update scratch

  k0_cvt<<<96, 256, 0, stream>>>(W_left, W_lgate, W_right, W_rgate, W_ogate, W_out, wts);
  k1a_ln<<<4096, 256, 0, stream>>>(z, lnw, lnb, znS);
  k1b_proj<<<4096, 256, 0, stream>>>(znS, pmask, b_lgate, b_rgate, wts, left_t, right_t);
  k2_einsum<<<dim3(8,8,128), 256, 0, stream>>>(left_t, right_t, upd16);
  k3a_ln<<<dim3(512,4), 256, 0, stream>>>(upd16, onw, onb, left_t /*znu*/);
  k3b_out<<<4096, 256, 0, stream>>>(left_t /*znu*/, znS, pmask, b_ogate, wts, (float*)d_out);
}